// Round 6
// baseline (292.006 us; speedup 1.0000x reference)
//
#include <hip/hip_runtime.h>
#include <hip/hip_fp16.h>
#include <math.h>

#define BB 8
#define HH 384
#define WW 768
#define HW (HH * WW)
#define NPIX (BB * HW)

#define TX 64
#define TY 16
#define HX (TX + 6)      // 70
#define HY (TY + 6)      // 22
#define LSTR 72          // LDS row stride in Pair4 elements
#define TILES_X (WW / TX)            // 12
#define TILES_Y (HH / TY)            // 24
#define NTILE (TILES_X * TILES_Y)    // 288 per image
#define GRID (NTILE * BB)            // 2304

// ---------- exact bilinear (feeds binary occ -> must stay bit-stable) ----------
struct Bil { int x0, x1, y0, y1; float wx, wy; };

__device__ __forceinline__ Bil bilin_setup(float fx, float fy, int x, int y) {
    Bil s;
    float gx = fminf(fmaxf(fx + (float)x, 0.0f), (float)(WW - 1));
    float gy = fminf(fmaxf(fy + (float)y, 0.0f), (float)(HH - 1));
    float x0f = floorf(gx), y0f = floorf(gy);
    s.wx = gx - x0f;
    s.wy = gy - y0f;
    s.x0 = (int)x0f;
    s.y0 = (int)y0f;
    s.x1 = min(s.x0 + 1, WW - 1);
    s.y1 = min(s.y0 + 1, HH - 1);
    return s;
}

__device__ __forceinline__ float bilin(const float* __restrict__ pl, const Bil& s) {
    float v00 = pl[s.y0 * WW + s.x0];
    float v01 = pl[s.y0 * WW + s.x1];
    float v10 = pl[s.y1 * WW + s.x0];
    float v11 = pl[s.y1 * WW + s.x1];
    float iwx = 1.0f - s.wx, iwy = 1.0f - s.wy;
    return v00 * iwx * iwy + v01 * s.wx * iwy + v10 * iwx * s.wy + v11 * s.wx * s.wy;
}

// ---------- fast bilinear (image gathers; loss-tolerant) ----------
struct FBil { int off; float wx, wy; };

__device__ __forceinline__ FBil fast_setup(float fx, float fy, int x, int y) {
    FBil s;
    float gx = fminf(fmaxf(fx + (float)x, 0.0f), (float)(WW - 1));
    float gy = fminf(fmaxf(fy + (float)y, 0.0f), (float)(HH - 1));
    int x0 = min((int)floorf(gx), WW - 2);
    int y0 = min((int)floorf(gy), HH - 2);
    s.wx = gx - (float)x0;
    s.wy = gy - (float)y0;
    s.off = y0 * WW + x0;
    return s;
}

__device__ __forceinline__ float fbil(const float* __restrict__ pl, const FBil& s) {
    const float* q = pl + s.off;
    float v00 = q[0], v01 = q[1], v10 = q[WW], v11 = q[WW + 1];
    float top = fmaf(s.wx, v01 - v00, v00);
    float bot = fmaf(s.wx, v11 - v10, v10);
    return fmaf(s.wy, bot - top, top);
}

__device__ __forceinline__ float gray255(float r, float g, float b) {
    return (0.2989f * r + 0.587f * g + 0.114f * b) * 255.0f;
}

__device__ __forceinline__ float robust04(float a) {
    // pow(|a| + 0.01, 0.4) via HW log2/exp2 (arg always > 0)
    float v = fabsf(a) + 0.01f;
    return __builtin_amdgcn_exp2f(0.4f * __builtin_amdgcn_logf(v));
}

struct __align__(8) Pair4 {
    __half2 fw;   // (inten1, inten2w) — forward census pair
    __half2 bw;   // (inten2, inten1w) — backward census pair
};

// pacc layout per block: [pf, pb, mf, mb, cf, cb]
__global__ __launch_bounds__(256) void fused_kernel(
        const float* __restrict__ img1, const float* __restrict__ img2,
        const float* __restrict__ ffw, const float* __restrict__ fbw,
        float* __restrict__ pacc, float* __restrict__ occ_out) {
    __shared__ Pair4 TILE[HY][LSTR];      // 22*72*8 = 12.7 KB
    __shared__ __half2 MASK[TY][TX];      // (mf, mb) packed, 4 KB
    __shared__ float red[4][6];

    // XCD swizzle: under round-robin dispatch, XCD k gets image k's 288 tiles.
    const int img = blockIdx.x & 7;
    const int t = blockIdx.x >> 3;
    const int tyile = t / TILES_X;
    const int txile = t - tyile * TILES_X;
    const int gx0 = txile * TX - 3;
    const int gy0 = tyile * TY - 3;

    const float* i1 = img1 + img * 3 * HW;
    const float* i2 = img2 + img * 3 * HW;
    const float* f1 = ffw + img * 2 * HW;
    const float* f2 = fbw + img * 2 * HW;

    float s_pf = 0.f, s_pb = 0.f, s_mf = 0.f, s_mb = 0.f;

    // ---- Phase 1: build packed f16 intensity planes (tile + halo) in LDS;
    //      occ/masks/photo for interior pixels along the way. ----
    for (int i = threadIdx.x; i < HX * HY; i += 256) {
        int ly = i / HX;
        int lx = i - ly * HX;
        int gx = gx0 + lx;
        int gy = gy0 + ly;
        bool inimg = (gx >= 0) & (gx < WW) & (gy >= 0) & (gy < HH);
        float v1 = 0.f, v2 = 0.f, v1w = 0.f, v2w = 0.f;
        if (inimg) {
            int p = gy * WW + gx;
            float fx = f1[p], fy = f1[HW + p];
            float bx = f2[p], by = f2[HW + p];
            float a0 = i1[p], a1 = i1[HW + p], a2 = i1[2 * HW + p];
            float c0 = i2[p], c1 = i2[HW + p], c2 = i2[2 * HW + p];

            // image gathers: fast shared-base path (feeds losses only)
            FBil qf = fast_setup(fx, fy, gx, gy);
            FBil qb = fast_setup(bx, by, gx, gy);
            float w20 = fbil(i2, qf);
            float w21 = fbil(i2 + HW, qf);
            float w22 = fbil(i2 + 2 * HW, qf);
            float w10 = fbil(i1, qb);
            float w11 = fbil(i1 + HW, qb);
            float w12 = fbil(i1 + 2 * HW, qb);

            v1 = gray255(a0, a1, a2);
            v2 = gray255(c0, c1, c2);
            v2w = gray255(w20, w21, w22);
            v1w = gray255(w10, w11, w12);

            bool interior = (lx >= 3) & (lx < 3 + TX) & (ly >= 3) & (ly < 3 + TY);
            if (interior) {
                // flow gathers: exact path (feeds binary occ)
                Bil sf = bilin_setup(fx, fy, gx, gy);
                Bil sb = bilin_setup(bx, by, gx, gy);
                float wbx = bilin(f2, sf), wby = bilin(f2 + HW, sf);
                float wfx = bilin(f1, sb), wfy = bilin(f1 + HW, sb);

                float dfx = fx + wbx, dfy = fy + wby;
                float magf = dfx * dfx + dfy * dfy;
                float fmf = fx * fx + fy * fy + wbx * wbx + wby * wby;
                float occf = (magf > 0.01f * fmf + 0.5f) ? 1.0f : 0.0f;
                float mf = 1.0f - occf;

                float dbx = bx + wfx, dby = by + wfy;
                float magb = dbx * dbx + dby * dby;
                float fmb = bx * bx + by * by + wfx * wfx + wfy * wfy;
                float occb = (magb > 0.01f * fmb + 0.5f) ? 1.0f : 0.0f;
                float mb = 1.0f - occb;

                MASK[ly - 3][lx - 3] = __floats2half2_rn(mf, mb);
                occ_out[img * HW + p] = occf;

                s_pf += (robust04(a0 - w20) + robust04(a1 - w21) + robust04(a2 - w22)) * mf;
                s_pb += (robust04(c0 - w10) + robust04(c1 - w11) + robust04(c2 - w12)) * mb;
                s_mf += mf;
                s_mb += mb;
            }
        }
        Pair4 pr;
        pr.fw = __floats2half2_rn(v1, v2w);
        pr.bw = __floats2half2_rn(v2, v1w);
        TILE[ly][lx] = pr;
    }
    __syncthreads();

    // ---- Phase 2: 49-tap census from LDS. Lane = tile column (8 B lane
    //      stride -> structural-minimum LDS banking, no excess conflicts);
    //      each thread owns 4 vertically-consecutive pixels, so each tap
    //      (10 rows x 7 cols window union) is loaded+converted once and
    //      reused by up to 4 pixels. ----
    float s_cf = 0.f, s_cb = 0.f;
    {
        const int lx = threadIdx.x & 63;          // tile column 0..63
        const int band = threadIdx.x >> 6;        // row group 0..3
        const int r0 = band * 4;                  // first interior row owned
        float2 cf[4], cb[4];
#pragma unroll
        for (int j = 0; j < 4; ++j) {
            Pair4 c = TILE[r0 + 3 + j][lx + 3];
            cf[j] = __half22float2(c.fw);
            cb[j] = __half22float2(c.bw);
        }
        float dsf[4] = {0.f, 0.f, 0.f, 0.f};
        float dsb[4] = {0.f, 0.f, 0.f, 0.f};
#pragma unroll
        for (int ty = 0; ty < 10; ++ty) {
#pragma unroll
            for (int dx = 0; dx < 7; ++dx) {
                Pair4 v = TILE[r0 + ty][lx + dx];
                float2 vf = __half22float2(v.fw);
                float2 vb = __half22float2(v.bw);
#pragma unroll
                for (int j = 0; j < 4; ++j) {
                    if (ty - j < 0 || ty - j > 6) continue;  // static guard
                    // center tap contributes exactly 0 — harmless to include
                    float u1 = vf.x - cf[j].x;
                    float u2 = vf.y - cf[j].y;
                    float t1 = u1 * __builtin_amdgcn_rsqf(fmaf(u1, u1, 0.81f));
                    float t2 = u2 * __builtin_amdgcn_rsqf(fmaf(u2, u2, 0.81f));
                    float df = t1 - t2;
                    float d2 = df * df;
                    dsf[j] = fmaf(d2, __builtin_amdgcn_rcpf(0.1f + d2), dsf[j]);

                    float w1 = vb.x - cb[j].x;
                    float w2 = vb.y - cb[j].y;
                    float q1 = w1 * __builtin_amdgcn_rsqf(fmaf(w1, w1, 0.81f));
                    float q2 = w2 * __builtin_amdgcn_rsqf(fmaf(w2, w2, 0.81f));
                    float db = q1 - q2;
                    float e2 = db * db;
                    dsb[j] = fmaf(e2, __builtin_amdgcn_rcpf(0.1f + e2), dsb[j]);
                }
            }
        }
#pragma unroll
        for (int j = 0; j < 4; ++j) {
            float2 m = __half22float2(MASK[r0 + j][lx]);
            s_cf += robust04(dsf[j]) * m.x;
            s_cb += robust04(dsb[j]) * m.y;
        }
    }

    // ---- Reduce 6 partials across the block. ----
    const int band = threadIdx.x >> 6;
    for (int o = 32; o > 0; o >>= 1) {
        s_pf += __shfl_down(s_pf, o, 64);
        s_pb += __shfl_down(s_pb, o, 64);
        s_mf += __shfl_down(s_mf, o, 64);
        s_mb += __shfl_down(s_mb, o, 64);
        s_cf += __shfl_down(s_cf, o, 64);
        s_cb += __shfl_down(s_cb, o, 64);
    }
    if ((threadIdx.x & 63) == 0) {
        red[band][0] = s_pf; red[band][1] = s_pb;
        red[band][2] = s_mf; red[band][3] = s_mb;
        red[band][4] = s_cf; red[band][5] = s_cb;
    }
    __syncthreads();
    if (threadIdx.x == 0) {
        float r0 = 0.f, r1 = 0.f, r2 = 0.f, r3 = 0.f, r4 = 0.f, r5 = 0.f;
        for (int i = 0; i < 4; ++i) {
            r0 += red[i][0]; r1 += red[i][1]; r2 += red[i][2];
            r3 += red[i][3]; r4 += red[i][4]; r5 += red[i][5];
        }
        float* o = pacc + blockIdx.x * 6;
        o[0] = r0; o[1] = r1; o[2] = r2; o[3] = r3; o[4] = r4; o[5] = r5;
    }
}

__global__ __launch_bounds__(256) void finalize_kernel(
        const float* __restrict__ pacc, float* __restrict__ out) {
    float s0 = 0.f, s1 = 0.f, s2 = 0.f, s3 = 0.f, s4 = 0.f, s5 = 0.f;
    for (int i = threadIdx.x; i < GRID; i += 256) {
        const float* o = pacc + i * 6;
        s0 += o[0]; s1 += o[1]; s2 += o[2];
        s3 += o[3]; s4 += o[4]; s5 += o[5];
    }
    for (int o = 32; o > 0; o >>= 1) {
        s0 += __shfl_down(s0, o, 64);
        s1 += __shfl_down(s1, o, 64);
        s2 += __shfl_down(s2, o, 64);
        s3 += __shfl_down(s3, o, 64);
        s4 += __shfl_down(s4, o, 64);
        s5 += __shfl_down(s5, o, 64);
    }
    __shared__ float red[4][6];
    int w = threadIdx.x >> 6;
    if ((threadIdx.x & 63) == 0) {
        red[w][0] = s0; red[w][1] = s1; red[w][2] = s2;
        red[w][3] = s3; red[w][4] = s4; red[w][5] = s5;
    }
    __syncthreads();
    if (threadIdx.x == 0) {
        float t0 = 0.f, t1 = 0.f, t2 = 0.f, t3 = 0.f, t4 = 0.f, t5 = 0.f;
        for (int i = 0; i < 4; ++i) {
            t0 += red[i][0]; t1 += red[i][1]; t2 += red[i][2];
            t3 += red[i][3]; t4 += red[i][4]; t5 += red[i][5];
        }
        float denf = t2 * 2.0f + 1e-6f;
        float denb = t3 * 2.0f + 1e-6f;
        float photo = t0 / denf + t1 / denb;
        float cens = t4 / denf + t5 / denb;
        out[0] = photo + cens;
        out[1] = photo;
        out[2] = cens;
    }
}

extern "C" void kernel_launch(void* const* d_in, const int* in_sizes, int n_in,
                              void* d_out, int out_size, void* d_ws, size_t ws_size,
                              hipStream_t stream) {
    const float* img1 = (const float*)d_in[0];
    const float* img2 = (const float*)d_in[1];
    const float* ffw = (const float*)d_in[2];
    const float* fbw = (const float*)d_in[3];
    float* out = (float*)d_out;
    float* pacc = (float*)d_ws;   // GRID*6 floats

    fused_kernel<<<GRID, 256, 0, stream>>>(img1, img2, ffw, fbw, pacc, out + 3);
    finalize_kernel<<<1, 256, 0, stream>>>(pacc, out);
}

// Round 7
// 241.621 us; speedup vs baseline: 1.2085x; 1.2085x over previous
//
#include <hip/hip_runtime.h>
#include <hip/hip_fp16.h>
#include <math.h>

#define BB 8
#define HH 384
#define WW 768
#define HW (HH * WW)
#define NPIX (BB * HW)

#define TX 64
#define TY 16
#define HX (TX + 6)      // 70
#define HY (TY + 6)      // 22
#define LSTR 72          // LDS row stride in Pair4 elements
#define TILES_X (WW / TX)            // 12
#define TILES_Y (HH / TY)            // 24
#define NTILE (TILES_X * TILES_Y)    // 288 per image
#define GRID (NTILE * BB)            // 2304

// ---------- exact bilinear (feeds binary occ -> must stay bit-stable) ----------
struct Bil { int x0, x1, y0, y1; float wx, wy; };

__device__ __forceinline__ Bil bilin_setup(float fx, float fy, int x, int y) {
    Bil s;
    float gx = fminf(fmaxf(fx + (float)x, 0.0f), (float)(WW - 1));
    float gy = fminf(fmaxf(fy + (float)y, 0.0f), (float)(HH - 1));
    float x0f = floorf(gx), y0f = floorf(gy);
    s.wx = gx - x0f;
    s.wy = gy - y0f;
    s.x0 = (int)x0f;
    s.y0 = (int)y0f;
    s.x1 = min(s.x0 + 1, WW - 1);
    s.y1 = min(s.y0 + 1, HH - 1);
    return s;
}

__device__ __forceinline__ float bilin(const float* __restrict__ pl, const Bil& s) {
    float v00 = pl[s.y0 * WW + s.x0];
    float v01 = pl[s.y0 * WW + s.x1];
    float v10 = pl[s.y1 * WW + s.x0];
    float v11 = pl[s.y1 * WW + s.x1];
    float iwx = 1.0f - s.wx, iwy = 1.0f - s.wy;
    return v00 * iwx * iwy + v01 * s.wx * iwy + v10 * iwx * s.wy + v11 * s.wx * s.wy;
}

// ---------- fast bilinear (image gathers; loss-tolerant) ----------
struct FBil { int off; float wx, wy; };

__device__ __forceinline__ FBil fast_setup(float fx, float fy, int x, int y) {
    FBil s;
    float gx = fminf(fmaxf(fx + (float)x, 0.0f), (float)(WW - 1));
    float gy = fminf(fmaxf(fy + (float)y, 0.0f), (float)(HH - 1));
    int x0 = min((int)floorf(gx), WW - 2);
    int y0 = min((int)floorf(gy), HH - 2);
    s.wx = gx - (float)x0;
    s.wy = gy - (float)y0;
    s.off = y0 * WW + x0;
    return s;
}

__device__ __forceinline__ float fbil(const float* __restrict__ pl, const FBil& s) {
    const float* q = pl + s.off;
    float v00 = q[0], v01 = q[1], v10 = q[WW], v11 = q[WW + 1];
    float top = fmaf(s.wx, v01 - v00, v00);
    float bot = fmaf(s.wx, v11 - v10, v10);
    return fmaf(s.wy, bot - top, top);
}

__device__ __forceinline__ float gray255(float r, float g, float b) {
    return (0.2989f * r + 0.587f * g + 0.114f * b) * 255.0f;
}

__device__ __forceinline__ float robust04(float a) {
    // pow(|a| + 0.01, 0.4) via HW log2/exp2 (arg always > 0)
    float v = fabsf(a) + 0.01f;
    return __builtin_amdgcn_exp2f(0.4f * __builtin_amdgcn_logf(v));
}

struct __align__(8) Pair4 {
    __half2 fw;   // (inten1, inten2w) — forward census pair
    __half2 bw;   // (inten2, inten1w) — backward census pair
};

// pacc layout per block: [pf, pb, mf, mb, cf, cb]
__global__ __launch_bounds__(256) void fused_kernel(
        const float* __restrict__ img1, const float* __restrict__ img2,
        const float* __restrict__ ffw, const float* __restrict__ fbw,
        float* __restrict__ pacc, float* __restrict__ occ_out) {
    __shared__ Pair4 TILE[HY][LSTR];      // 22*72*8 = 12.7 KB
    __shared__ __half2 MASK[TY][TX];      // (mf, mb) packed, 4 KB
    __shared__ float red[4][6];

    // XCD swizzle: under round-robin dispatch, XCD k gets image k's 288 tiles.
    const int img = blockIdx.x & 7;
    const int t = blockIdx.x >> 3;
    const int tyile = t / TILES_X;
    const int txile = t - tyile * TILES_X;
    const int gx0 = txile * TX - 3;
    const int gy0 = tyile * TY - 3;

    const float* i1 = img1 + img * 3 * HW;
    const float* i2 = img2 + img * 3 * HW;
    const float* f1 = ffw + img * 2 * HW;
    const float* f2 = fbw + img * 2 * HW;

    float s_pf = 0.f, s_pb = 0.f, s_mf = 0.f, s_mb = 0.f;

    // ---- Phase 1: build packed f16 intensity planes (tile + halo) in LDS;
    //      occ/masks/photo for interior pixels along the way. ----
    for (int i = threadIdx.x; i < HX * HY; i += 256) {
        int ly = i / HX;
        int lx = i - ly * HX;
        int gx = gx0 + lx;
        int gy = gy0 + ly;
        bool inimg = (gx >= 0) & (gx < WW) & (gy >= 0) & (gy < HH);
        float v1 = 0.f, v2 = 0.f, v1w = 0.f, v2w = 0.f;
        if (inimg) {
            int p = gy * WW + gx;
            float fx = f1[p], fy = f1[HW + p];
            float bx = f2[p], by = f2[HW + p];
            float a0 = i1[p], a1 = i1[HW + p], a2 = i1[2 * HW + p];
            float c0 = i2[p], c1 = i2[HW + p], c2 = i2[2 * HW + p];

            // image gathers: fast shared-base path (feeds losses only)
            FBil qf = fast_setup(fx, fy, gx, gy);
            FBil qb = fast_setup(bx, by, gx, gy);
            float w20 = fbil(i2, qf);
            float w21 = fbil(i2 + HW, qf);
            float w22 = fbil(i2 + 2 * HW, qf);
            float w10 = fbil(i1, qb);
            float w11 = fbil(i1 + HW, qb);
            float w12 = fbil(i1 + 2 * HW, qb);

            v1 = gray255(a0, a1, a2);
            v2 = gray255(c0, c1, c2);
            v2w = gray255(w20, w21, w22);
            v1w = gray255(w10, w11, w12);

            bool interior = (lx >= 3) & (lx < 3 + TX) & (ly >= 3) & (ly < 3 + TY);
            if (interior) {
                // flow gathers: exact path (feeds binary occ)
                Bil sf = bilin_setup(fx, fy, gx, gy);
                Bil sb = bilin_setup(bx, by, gx, gy);
                float wbx = bilin(f2, sf), wby = bilin(f2 + HW, sf);
                float wfx = bilin(f1, sb), wfy = bilin(f1 + HW, sb);

                float dfx = fx + wbx, dfy = fy + wby;
                float magf = dfx * dfx + dfy * dfy;
                float fmf = fx * fx + fy * fy + wbx * wbx + wby * wby;
                float occf = (magf > 0.01f * fmf + 0.5f) ? 1.0f : 0.0f;
                float mf = 1.0f - occf;

                float dbx = bx + wfx, dby = by + wfy;
                float magb = dbx * dbx + dby * dby;
                float fmb = bx * bx + by * by + wfx * wfx + wfy * wfy;
                float occb = (magb > 0.01f * fmb + 0.5f) ? 1.0f : 0.0f;
                float mb = 1.0f - occb;

                MASK[ly - 3][lx - 3] = __floats2half2_rn(mf, mb);
                occ_out[img * HW + p] = occf;

                s_pf += (robust04(a0 - w20) + robust04(a1 - w21) + robust04(a2 - w22)) * mf;
                s_pb += (robust04(c0 - w10) + robust04(c1 - w11) + robust04(c2 - w12)) * mb;
                s_mf += mf;
                s_mb += mb;
            }
        }
        Pair4 pr;
        pr.fw = __floats2half2_rn(v1, v2w);
        pr.bw = __floats2half2_rn(v2, v1w);
        TILE[ly][lx] = pr;
    }
    __syncthreads();

    // ---- Phase 2: 49-tap census from LDS. Lane = tile column (8 B lane
    //      stride -> conflict-free banking, verified round 6); each thread
    //      owns 4 vertically-consecutive pixels so each tap is loaded and
    //      converted once, reused by up to 4 pixels. ty loop kept DYNAMIC
    //      (#pragma unroll 1) to bound the scheduler's load-hoist scope —
    //      round 6's full static unroll pushed VGPR to 108 and tanked
    //      occupancy. j-guards are wave-uniform -> scalar pipe, ~free. ----
    float s_cf = 0.f, s_cb = 0.f;
    {
        const int lx = threadIdx.x & 63;          // tile column 0..63
        const int band = threadIdx.x >> 6;        // row group 0..3
        const int r0 = band * 4;                  // first interior row owned
        float2 cf[4], cb[4];
#pragma unroll
        for (int j = 0; j < 4; ++j) {
            Pair4 c = TILE[r0 + 3 + j][lx + 3];
            cf[j] = __half22float2(c.fw);
            cb[j] = __half22float2(c.bw);
        }
        float dsf[4] = {0.f, 0.f, 0.f, 0.f};
        float dsb[4] = {0.f, 0.f, 0.f, 0.f};
#pragma unroll 1
        for (int ty = 0; ty < 10; ++ty) {
            const int jlo = max(ty - 6, 0);       // wave-uniform bounds
            const int jhi = min(ty, 3);
#pragma unroll
            for (int dx = 0; dx < 7; ++dx) {
                Pair4 v = TILE[r0 + ty][lx + dx];
                float2 vf = __half22float2(v.fw);
                float2 vb = __half22float2(v.bw);
#pragma unroll
                for (int j = 0; j < 4; ++j) {
                    if (j < jlo || j > jhi) continue;   // uniform branch
                    // center tap contributes exactly 0 — harmless to include
                    float u1 = vf.x - cf[j].x;
                    float u2 = vf.y - cf[j].y;
                    float t1 = u1 * __builtin_amdgcn_rsqf(fmaf(u1, u1, 0.81f));
                    float t2 = u2 * __builtin_amdgcn_rsqf(fmaf(u2, u2, 0.81f));
                    float df = t1 - t2;
                    float d2 = df * df;
                    dsf[j] = fmaf(d2, __builtin_amdgcn_rcpf(0.1f + d2), dsf[j]);

                    float w1 = vb.x - cb[j].x;
                    float w2 = vb.y - cb[j].y;
                    float q1 = w1 * __builtin_amdgcn_rsqf(fmaf(w1, w1, 0.81f));
                    float q2 = w2 * __builtin_amdgcn_rsqf(fmaf(w2, w2, 0.81f));
                    float db = q1 - q2;
                    float e2 = db * db;
                    dsb[j] = fmaf(e2, __builtin_amdgcn_rcpf(0.1f + e2), dsb[j]);
                }
            }
        }
#pragma unroll
        for (int j = 0; j < 4; ++j) {
            float2 m = __half22float2(MASK[r0 + j][lx]);
            s_cf += robust04(dsf[j]) * m.x;
            s_cb += robust04(dsb[j]) * m.y;
        }
    }

    // ---- Reduce 6 partials across the block. ----
    const int band = threadIdx.x >> 6;
    for (int o = 32; o > 0; o >>= 1) {
        s_pf += __shfl_down(s_pf, o, 64);
        s_pb += __shfl_down(s_pb, o, 64);
        s_mf += __shfl_down(s_mf, o, 64);
        s_mb += __shfl_down(s_mb, o, 64);
        s_cf += __shfl_down(s_cf, o, 64);
        s_cb += __shfl_down(s_cb, o, 64);
    }
    if ((threadIdx.x & 63) == 0) {
        red[band][0] = s_pf; red[band][1] = s_pb;
        red[band][2] = s_mf; red[band][3] = s_mb;
        red[band][4] = s_cf; red[band][5] = s_cb;
    }
    __syncthreads();
    if (threadIdx.x == 0) {
        float r0 = 0.f, r1 = 0.f, r2 = 0.f, r3 = 0.f, r4 = 0.f, r5 = 0.f;
        for (int i = 0; i < 4; ++i) {
            r0 += red[i][0]; r1 += red[i][1]; r2 += red[i][2];
            r3 += red[i][3]; r4 += red[i][4]; r5 += red[i][5];
        }
        float* o = pacc + blockIdx.x * 6;
        o[0] = r0; o[1] = r1; o[2] = r2; o[3] = r3; o[4] = r4; o[5] = r5;
    }
}

__global__ __launch_bounds__(256) void finalize_kernel(
        const float* __restrict__ pacc, float* __restrict__ out) {
    float s0 = 0.f, s1 = 0.f, s2 = 0.f, s3 = 0.f, s4 = 0.f, s5 = 0.f;
    for (int i = threadIdx.x; i < GRID; i += 256) {
        const float* o = pacc + i * 6;
        s0 += o[0]; s1 += o[1]; s2 += o[2];
        s3 += o[3]; s4 += o[4]; s5 += o[5];
    }
    for (int o = 32; o > 0; o >>= 1) {
        s0 += __shfl_down(s0, o, 64);
        s1 += __shfl_down(s1, o, 64);
        s2 += __shfl_down(s2, o, 64);
        s3 += __shfl_down(s3, o, 64);
        s4 += __shfl_down(s4, o, 64);
        s5 += __shfl_down(s5, o, 64);
    }
    __shared__ float red[4][6];
    int w = threadIdx.x >> 6;
    if ((threadIdx.x & 63) == 0) {
        red[w][0] = s0; red[w][1] = s1; red[w][2] = s2;
        red[w][3] = s3; red[w][4] = s4; red[w][5] = s5;
    }
    __syncthreads();
    if (threadIdx.x == 0) {
        float t0 = 0.f, t1 = 0.f, t2 = 0.f, t3 = 0.f, t4 = 0.f, t5 = 0.f;
        for (int i = 0; i < 4; ++i) {
            t0 += red[i][0]; t1 += red[i][1]; t2 += red[i][2];
            t3 += red[i][3]; t4 += red[i][4]; t5 += red[i][5];
        }
        float denf = t2 * 2.0f + 1e-6f;
        float denb = t3 * 2.0f + 1e-6f;
        float photo = t0 / denf + t1 / denb;
        float cens = t4 / denf + t5 / denb;
        out[0] = photo + cens;
        out[1] = photo;
        out[2] = cens;
    }
}

extern "C" void kernel_launch(void* const* d_in, const int* in_sizes, int n_in,
                              void* d_out, int out_size, void* d_ws, size_t ws_size,
                              hipStream_t stream) {
    const float* img1 = (const float*)d_in[0];
    const float* img2 = (const float*)d_in[1];
    const float* ffw = (const float*)d_in[2];
    const float* fbw = (const float*)d_in[3];
    float* out = (float*)d_out;
    float* pacc = (float*)d_ws;   // GRID*6 floats

    fused_kernel<<<GRID, 256, 0, stream>>>(img1, img2, ffw, fbw, pacc, out + 3);
    finalize_kernel<<<1, 256, 0, stream>>>(pacc, out);
}